// Round 1
// baseline (1025.897 us; speedup 1.0000x reference)
//
#include <hip/hip_runtime.h>
#include <hip/hip_bf16.h>

typedef __bf16 bf16;
typedef bf16 bf16x8 __attribute__((ext_vector_type(8)));
typedef bf16 bf16x4 __attribute__((ext_vector_type(4)));
typedef float f32x16 __attribute__((ext_vector_type(16)));
typedef float f32x4 __attribute__((ext_vector_type(4)));

#define MFMA(a,b,c) __builtin_amdgcn_mfma_f32_32x32x16_bf16(a,b,c,0,0,0)

constexpr int S = 8192;                 // n*h tokens per batch
constexpr long long SB = (long long)S * S;
constexpr long long ATTN_ELEMS = 2 * SB;

// ---------------------------------------------------------------------------
// K1: QKV projection. grid 512 x 64 threads (1 wave). 32 rows per block.
// q is pre-scaled by 1/8 (exact pow2). v is written TRANSPOSED (vt[b][d][t])
// so the PV MFMA B-fragment is a contiguous 16B load.
// ---------------------------------------------------------------------------
__global__ __launch_bounds__(64) void qkv_kernel(
    const float* __restrict__ x, const float* __restrict__ wq,
    const float* __restrict__ wk, const float* __restrict__ wv,
    bf16* __restrict__ qb, bf16* __restrict__ kb, bf16* __restrict__ vt)
{
  __shared__ bf16 vtl[64 * 34];              // [d][t] tile, stride 34 (pad)
  const int lane = threadIdx.x;
  const int lo = lane & 31, hi = lane >> 5;
  const int m0 = blockIdx.x * 32;            // global row in [0,16384)

  // A fragments: x rows -> bf16.  A[m=lane%32][k=16s+8*hi+j]
  bf16x8 af[4];
  {
    const float* xr = x + (size_t)(m0 + lo) * 64 + hi * 8;
#pragma unroll
    for (int s = 0; s < 4; ++s) {
      const float* p = xr + 16 * s;
#pragma unroll
      for (int j = 0; j < 8; ++j) af[s][j] = (bf16)p[j];
    }
  }

  const float* wmats[3] = {wq, wk, wv};
#pragma unroll 1
  for (int mat = 0; mat < 3; ++mat) {
    const float* w = wmats[mat];
#pragma unroll 1
    for (int h = 0; h < 2; ++h) {
      f32x16 acc = {};
#pragma unroll
      for (int s = 0; s < 4; ++s) {
        const float* p = w + (size_t)(32 * h + lo) * 64 + hi * 8 + 16 * s;
        bf16x8 bfr;
#pragma unroll
        for (int j = 0; j < 8; ++j) bfr[j] = (bf16)p[j];
        acc = MFMA(af[s], bfr, acc);
      }
      const int col = 32 * h + lo;
#pragma unroll
      for (int i = 0; i < 16; ++i) {
        int row = (i & 3) + 8 * (i >> 2) + 4 * hi;
        float v = acc[i];
        if (mat == 0) {
          qb[(size_t)(m0 + row) * 64 + col] = (bf16)(v * 0.125f);
        } else if (mat == 1) {
          kb[(size_t)(m0 + row) * 64 + col] = (bf16)v;
        } else {
          vtl[col * 34 + row] = (bf16)v;     // stage for transpose
        }
      }
    }
  }
  __syncthreads();
  // vt writeout: vt[b][d][t], coalesced along t
  const int b = m0 >> 13;
  const int t0 = m0 & 8191;
#pragma unroll 1
  for (int i = 0; i < 32; ++i) {
    int d = 2 * i + hi;
    vt[(size_t)b * (64 * 8192) + (size_t)d * 8192 + t0 + lo] = vtl[d * 34 + lo];
  }
}

// ---------------------------------------------------------------------------
// K2: fused attention. grid 512 x 256 threads (4 waves).
// Block = 32 q-rows of one batch.  Wave wt owns t-columns {128c+32*wt..+32}.
// S^T orientation: acc = MFMA(kf, qf) => lane (lo,hi) holds q-row m=lo,
// t-slots (i&3)+8*(i>>2)+4*hi.  Softmax denom is a per-lane scalar.
// Sweep 1: l += exp(S).  Sweep 2: recompute S, 4x dwordx4 NT attn stores,
// P -> wave-private LDS via 4x b64 packed writes, O += P@V.
// Per-iter schedule: ALL vmem loads first, NT stores LAST (single in-order
// vmcnt on gfx9 => stores before loads put store-ack on the MFMA path).
// ---------------------------------------------------------------------------
__global__ __launch_bounds__(256) void attn_kernel(
    const bf16* __restrict__ qb, const bf16* __restrict__ kb,
    const bf16* __restrict__ vt, float* __restrict__ attn_out,
    float* __restrict__ o_ws)
{
  __shared__ bf16 plds[4 * 32 * 40];   // per-wave 32x32 P tile, stride 40 bf16
  __shared__ float olds[32 * 65];      // O reduction buffer (pad 65)
  __shared__ float l4[4 * 32];
  __shared__ float linv[32];

  const int tid = threadIdx.x;
  const int lane = tid & 63;
  const int wt = tid >> 6;
  const int lo = lane & 31, hi = lane >> 5;

  // XCD swizzle: each XCD (bx%8) handles a single batch -> K,Vt L2-resident
  const int bx = blockIdx.x;
  const int g = bx >> 3, r = bx & 7;
  const int b = r >> 2;
  const int m0 = (g * 4 + (r & 3)) * 32;     // q-row block within batch

  for (int i = tid; i < 32 * 65; i += 256) olds[i] = 0.0f;

  // Q fragments (persist across both sweeps)
  bf16x8 qf[4];
  {
    const bf16* qr = qb + ((size_t)b * S + m0 + lo) * 64 + hi * 8;
#pragma unroll
    for (int s = 0; s < 4; ++s) qf[s] = *(const bf16x8*)(qr + 16 * s);
  }
  const bf16* kbase = kb + (size_t)b * S * 64;
  const bf16* vbase = vt + (size_t)b * 64 * S;

  // ---------------- sweep 1: row sums (per-lane scalar) ----------------
  float e0 = 0.0f, e1 = 0.0f, e2 = 0.0f, e3 = 0.0f;
#pragma unroll 1
  for (int c = 0; c < 64; ++c) {
    const int t0 = c * 128 + wt * 32;
    const bf16* krow = kbase + (size_t)(t0 + lo) * 64 + hi * 8;
    f32x16 acc = {};
#pragma unroll
    for (int s = 0; s < 4; ++s) {
      bf16x8 kf = *(const bf16x8*)(krow + 16 * s);
      acc = MFMA(kf, qf[s], acc);          // S^T: lane holds q-row m=lo
    }
#pragma unroll
    for (int i = 0; i < 16; i += 4) {
      e0 += __expf(acc[i]);
      e1 += __expf(acc[i + 1]);
      e2 += __expf(acc[i + 2]);
      e3 += __expf(acc[i + 3]);
    }
  }
  float lsum = (e0 + e1) + (e2 + e3);
  lsum += __shfl_xor(lsum, 32);            // combine the two hi-halves
  if (hi == 0) l4[wt * 32 + lo] = lsum;
  __syncthreads();
  if (tid < 32)
    linv[tid] = 1.0f / (l4[tid] + l4[32 + tid] + l4[64 + tid] + l4[96 + tid]);
  __syncthreads();
  const float li = linv[lo];

  // ---------------- sweep 2: write attn, accumulate O ----------------
  f32x16 oacc0 = {}, oacc1 = {};
  bf16* pw = plds + wt * 1280;                     // wave-private P tile
  float* aout = attn_out + (size_t)b * SB + (size_t)m0 * S;
  const size_t rowbase = (size_t)lo * S;           // this lane's q-row
#pragma unroll 1
  for (int c = 0; c < 64; ++c) {
    const int t0 = c * 128 + wt * 32;
    // --- all global loads issued up front ---
    const bf16* krow = kbase + (size_t)(t0 + lo) * 64 + hi * 8;
    bf16x8 kf0 = *(const bf16x8*)(krow);
    bf16x8 kf1 = *(const bf16x8*)(krow + 16);
    bf16x8 kf2 = *(const bf16x8*)(krow + 32);
    bf16x8 kf3 = *(const bf16x8*)(krow + 48);
    const bf16* vrow = vbase + (size_t)lo * S + t0 + 8 * hi;
    bf16x8 va0 = *(const bf16x8*)(vrow);                       // d=lo,    s=0
    bf16x8 va1 = *(const bf16x8*)(vrow + 16);                  // d=lo,    s=1
    bf16x8 vb0 = *(const bf16x8*)(vrow + (size_t)32 * S);      // d=lo+32, s=0
    bf16x8 vb1 = *(const bf16x8*)(vrow + (size_t)32 * S + 16); // d=lo+32, s=1

    f32x16 acc = {};
    acc = MFMA(kf0, qf[0], acc);
    acc = MFMA(kf1, qf[1], acc);
    acc = MFMA(kf2, qf[2], acc);
    acc = MFMA(kf3, qf[3], acc);

    float p[16];
#pragma unroll
    for (int i = 0; i < 16; ++i) p[i] = __expf(acc[i]) * li;

    // P -> LDS, packed b64 writes: t-slot of elem i is (i&3)+8*(i>>2)+4*hi
#pragma unroll
    for (int gq = 0; gq < 4; ++gq) {
      bf16x4 pk;
      pk[0] = (bf16)p[4 * gq];
      pk[1] = (bf16)p[4 * gq + 1];
      pk[2] = (bf16)p[4 * gq + 2];
      pk[3] = (bf16)p[4 * gq + 3];
      *(bf16x4*)(pw + lo * 40 + 8 * gq + 4 * hi) = pk;
    }
    // PV: O[32 x 64] += P(32x32) @ V(32x64); A from LDS (same-wave, in-order)
#pragma unroll
    for (int s = 0; s < 2; ++s) {
      bf16x8 pf = *(const bf16x8*)(pw + lo * 40 + 16 * s + 8 * hi);
      oacc0 = MFMA(pf, s ? va1 : va0, oacc0);
      oacc1 = MFMA(pf, s ? vb1 : vb0, oacc1);
    }
    // --- NT attn stores LAST: nothing waits on them inside this iter ---
#pragma unroll
    for (int gq = 0; gq < 4; ++gq) {
      f32x4 st = { p[4 * gq], p[4 * gq + 1], p[4 * gq + 2], p[4 * gq + 3] };
      __builtin_nontemporal_store(st,
          (f32x4*)(aout + rowbase + t0 + 8 * gq + 4 * hi));
    }
  }
  // reduce partial O across the 4 waves
#pragma unroll
  for (int i = 0; i < 16; ++i) {
    int row = (i & 3) + 8 * (i >> 2) + 4 * hi;
    atomicAdd(&olds[row * 65 + lo], oacc0[i]);
    atomicAdd(&olds[row * 65 + 32 + lo], oacc1[i]);
  }
  __syncthreads();
#pragma unroll
  for (int k = 0; k < 8; ++k) {
    int idx = k * 256 + tid;
    int row = idx >> 6, col = idx & 63;
    o_ws[((size_t)b * S + m0 + row) * 64 + col] = olds[row * 65 + col];
  }
}

// ---------------------------------------------------------------------------
// K3/K4: MLP with compensated bf16 MFMA (hi/lo split, 3-term products) so the
// MLP contributes ~2^-17 relative error. gelu exact via erff.
// ---------------------------------------------------------------------------
__device__ inline float gelu_exact(float v) {
  return 0.5f * v * (1.0f + erff(v * 0.70710678118654752f));
}

__global__ __launch_bounds__(256) void mlp1_kernel(
    const float* __restrict__ o_ws, const float* __restrict__ w1,
    const float* __restrict__ b1, bf16* __restrict__ hhi, bf16* __restrict__ hlo)
{
  const int tid = threadIdx.x;
  const int lane = tid & 63;
  const int wid = tid >> 6;
  const int lo = lane & 31, hi = lane >> 5;
  const int mt = blockIdx.x & 31, nt = blockIdx.x >> 5;
  const int m0 = mt * 64 + (wid & 1) * 32;
  const int f0 = nt * 64 + (wid >> 1) * 32;

  f32x16 acc = {};
  const float* arow = o_ws + (size_t)(m0 + lo) * 512 + hi * 8;
  const float* brow = w1 + (size_t)(f0 + lo) * 512 + hi * 8;
#pragma unroll 1
  for (int s = 0; s < 32; ++s) {
    const float* pa = arow + 16 * s;
    const float* pb = brow + 16 * s;
    bf16x8 ah, al, bh, bl;
#pragma unroll
    for (int j = 0; j < 8; ++j) {
      float a = pa[j];  bf16 h = (bf16)a;  ah[j] = h;  al[j] = (bf16)(a - (float)h);
      float bv = pb[j]; bf16 g = (bf16)bv; bh[j] = g;  bl[j] = (bf16)(bv - (float)g);
    }
    acc = MFMA(ah, bh, acc);
    acc = MFMA(ah, bl, acc);
    acc = MFMA(al, bh, acc);
  }
  const int f = f0 + lo;
  const float bias = b1[f];
#pragma unroll
  for (int i = 0; i < 16; ++i) {
    int m = m0 + (i & 3) + 8 * (i >> 2) + 4 * hi;
    float gv = gelu_exact(acc[i] + bias);
    bf16 h = (bf16)gv;
    hhi[(size_t)m * 1024 + f] = h;
    hlo[(size_t)m * 1024 + f] = (bf16)(gv - (float)h);
  }
}

__global__ __launch_bounds__(256) void mlp2_kernel(
    const bf16* __restrict__ hhi, const bf16* __restrict__ hlo,
    const float* __restrict__ w2, const float* __restrict__ b2,
    float* __restrict__ out2)
{
  const int tid = threadIdx.x;
  const int lane = tid & 63;
  const int wid = tid >> 6;
  const int lo = lane & 31, hi = lane >> 5;
  const int mt = blockIdx.x & 31, nt = blockIdx.x >> 5;
  const int m0 = mt * 64 + (wid & 1) * 32;
  const int e0 = nt * 64 + (wid >> 1) * 32;

  f32x16 acc = {};
  const bf16* ahr = hhi + (size_t)(m0 + lo) * 1024 + hi * 8;
  const bf16* alr = hlo + (size_t)(m0 + lo) * 1024 + hi * 8;
  const float* brow = w2 + (size_t)(e0 + lo) * 1024 + hi * 8;
#pragma unroll 1
  for (int s = 0; s < 64; ++s) {
    bf16x8 ah = *(const bf16x8*)(ahr + 16 * s);
    bf16x8 al = *(const bf16x8*)(alr + 16 * s);
    const float* pb = brow + 16 * s;
    bf16x8 bh, bl;
#pragma unroll
    for (int j = 0; j < 8; ++j) {
      float bv = pb[j]; bf16 g = (bf16)bv; bh[j] = g; bl[j] = (bf16)(bv - (float)g);
    }
    acc = MFMA(ah, bh, acc);
    acc = MFMA(al, bh, acc);
    acc = MFMA(ah, bl, acc);
  }
  const int e = e0 + lo;
  const float bias = b2[e];
#pragma unroll
  for (int i = 0; i < 16; ++i) {
    int m = m0 + (i & 3) + 8 * (i >> 2) + 4 * hi;
    out2[(size_t)m * 512 + e] = acc[i] + bias;
  }
}

// ---------------------------------------------------------------------------
extern "C" void kernel_launch(void* const* d_in, const int* in_sizes, int n_in,
                              void* d_out, int out_size, void* d_ws, size_t ws_size,
                              hipStream_t stream) {
  const float* x  = (const float*)d_in[0];
  const float* wq = (const float*)d_in[1];
  const float* wk = (const float*)d_in[2];
  const float* wv = (const float*)d_in[3];
  const float* w1 = (const float*)d_in[4];
  const float* b1 = (const float*)d_in[5];
  const float* w2 = (const float*)d_in[6];
  const float* b2 = (const float*)d_in[7];
  float* out = (float*)d_out;

  char* ws = (char*)d_ws;
  bf16* qb   = (bf16*)(ws);                       // 2 MB
  bf16* kb   = (bf16*)(ws + (2u << 20));          // 2 MB
  bf16* vtb  = (bf16*)(ws + (4u << 20));          // 2 MB (transposed V)
  float* ob  = (float*)(ws + (6u << 20));         // 4 MB (attention output)
  bf16* hhi  = (bf16*)(ws + (10u << 20));         // 4 MB
  bf16* hlo  = (bf16*)(ws + (14u << 20));         // 4 MB  -> 18 MB total

  qkv_kernel<<<512, 64, 0, stream>>>(x, wq, wk, wv, qb, kb, vtb);
  attn_kernel<<<512, 256, 0, stream>>>(qb, kb, vtb, out, ob);
  mlp1_kernel<<<512, 256, 0, stream>>>(ob, w1, b1, hhi, hlo);
  mlp2_kernel<<<256, 256, 0, stream>>>(hhi, hlo, w2, b2, out + ATTN_ELEMS);
}

// Round 2
// 749.280 us; speedup vs baseline: 1.3692x; 1.3692x over previous
//
#include <hip/hip_runtime.h>
#include <hip/hip_bf16.h>

typedef __bf16 bf16;
typedef bf16 bf16x8 __attribute__((ext_vector_type(8)));
typedef float f32x16 __attribute__((ext_vector_type(16)));

#define MFMA(a,b,c) __builtin_amdgcn_mfma_f32_32x32x16_bf16(a,b,c,0,0,0)

constexpr int S = 8192;                 // n*h tokens per batch
constexpr long long SB = (long long)S * S;
constexpr long long ATTN_ELEMS = 2 * SB;

// ---------------------------------------------------------------------------
// K1: QKV projection. grid 512 x 64 threads (1 wave). 32 rows per block.
// q is pre-scaled by 1/8 (exact pow2). v is written TRANSPOSED (vt[b][d][t])
// so the PV MFMA B-fragment is a contiguous 16B load.
// ---------------------------------------------------------------------------
__global__ __launch_bounds__(64) void qkv_kernel(
    const float* __restrict__ x, const float* __restrict__ wq,
    const float* __restrict__ wk, const float* __restrict__ wv,
    bf16* __restrict__ qb, bf16* __restrict__ kb, bf16* __restrict__ vt)
{
  __shared__ bf16 vtl[64 * 34];              // [d][t] tile, stride 34 (pad)
  const int lane = threadIdx.x;
  const int lo = lane & 31, hi = lane >> 5;
  const int m0 = blockIdx.x * 32;            // global row in [0,16384)

  // A fragments: x rows -> bf16.  A[m=lane%32][k=16s+8*hi+j]
  bf16x8 af[4];
  {
    const float* xr = x + (size_t)(m0 + lo) * 64 + hi * 8;
#pragma unroll
    for (int s = 0; s < 4; ++s) {
      const float* p = xr + 16 * s;
#pragma unroll
      for (int j = 0; j < 8; ++j) af[s][j] = (bf16)p[j];
    }
  }

  const float* wmats[3] = {wq, wk, wv};
#pragma unroll 1
  for (int mat = 0; mat < 3; ++mat) {
    const float* w = wmats[mat];
#pragma unroll 1
    for (int h = 0; h < 2; ++h) {
      f32x16 acc = {};
#pragma unroll
      for (int s = 0; s < 4; ++s) {
        const float* p = w + (size_t)(32 * h + lo) * 64 + hi * 8 + 16 * s;
        bf16x8 bfr;
#pragma unroll
        for (int j = 0; j < 8; ++j) bfr[j] = (bf16)p[j];
        acc = MFMA(af[s], bfr, acc);
      }
      const int col = 32 * h + lo;
#pragma unroll
      for (int i = 0; i < 16; ++i) {
        int row = (i & 3) + 8 * (i >> 2) + 4 * hi;
        float v = acc[i];
        if (mat == 0) {
          qb[(size_t)(m0 + row) * 64 + col] = (bf16)(v * 0.125f);
        } else if (mat == 1) {
          kb[(size_t)(m0 + row) * 64 + col] = (bf16)v;
        } else {
          vtl[col * 34 + row] = (bf16)v;     // stage for transpose
        }
      }
    }
  }
  __syncthreads();
  // vt writeout: vt[b][d][t], coalesced along t
  const int b = m0 >> 13;
  const int t0 = m0 & 8191;
#pragma unroll 1
  for (int i = 0; i < 32; ++i) {
    int d = 2 * i + hi;
    vt[(size_t)b * (64 * 8192) + (size_t)d * 8192 + t0 + lo] = vtl[d * 34 + lo];
  }
}

// ---------------------------------------------------------------------------
// K2: fused attention. grid 512 x 256 threads (4 waves).
// Block = 32 q-rows of one batch.  Wave wt owns t-columns {128c+32*wt..+32}.
// Sweep 1 uses S^T orientation (MFMA(kf,qf)): lane (lo,hi) holds q-row lo
// -> softmax denominator is a per-lane scalar (no butterfly, no LDS).
// Sweep 2 uses NORMAL orientation (MFMA(qf,kf)): lane holds 16 q-rows at
// t-col lo -> attn stores are per-instruction coalesced (2 rows x 128B).
// K and V fragments are DOUBLE-BUFFERED: iteration c+1's 8 loads are issued
// BEFORE iteration c's 16 NT stores, so (in-order vmcnt retirement) the
// s_waitcnt feeding the MFMAs never drains the stores -> store completion
// gets a full iteration of slack off the critical path.
// ---------------------------------------------------------------------------
__global__ __launch_bounds__(256) void attn_kernel(
    const bf16* __restrict__ qb, const bf16* __restrict__ kb,
    const bf16* __restrict__ vt, float* __restrict__ attn_out,
    float* __restrict__ o_ws)
{
  __shared__ bf16 plds[4 * 32 * 40];   // per-wave 32x32 P tile, stride 40 bf16
  __shared__ float olds[32 * 65];      // O reduction buffer (pad 65)
  __shared__ float l4[4 * 32];
  __shared__ float linv[32];

  const int tid = threadIdx.x;
  const int lane = tid & 63;
  const int wt = tid >> 6;
  const int lo = lane & 31, hi = lane >> 5;

  // XCD swizzle: each XCD (bx%8) handles a single batch -> K,Vt L2-resident
  const int bx = blockIdx.x;
  const int g = bx >> 3, r = bx & 7;
  const int b = r >> 2;
  const int m0 = (g * 4 + (r & 3)) * 32;     // q-row block within batch

  for (int i = tid; i < 32 * 65; i += 256) olds[i] = 0.0f;

  // Q fragments (persist across both sweeps; same frag serves A and B roles)
  bf16x8 qf[4];
  {
    const bf16* qr = qb + ((size_t)b * S + m0 + lo) * 64 + hi * 8;
#pragma unroll
    for (int s = 0; s < 4; ++s) qf[s] = *(const bf16x8*)(qr + 16 * s);
  }
  const bf16* kbase = kb + (size_t)b * S * 64;
  const bf16* vbase = vt + (size_t)b * 64 * S;

  // ---------------- sweep 1: row sums, S^T (per-lane scalar) ----------------
  float e0 = 0.0f, e1 = 0.0f, e2 = 0.0f, e3 = 0.0f;
#pragma unroll 1
  for (int c = 0; c < 64; ++c) {
    const int t0 = c * 128 + wt * 32;
    const bf16* krow = kbase + (size_t)(t0 + lo) * 64 + hi * 8;
    f32x16 acc = {};
#pragma unroll
    for (int s = 0; s < 4; ++s) {
      bf16x8 kf = *(const bf16x8*)(krow + 16 * s);
      acc = MFMA(kf, qf[s], acc);          // S^T: lane holds q-row m=lo
    }
#pragma unroll
    for (int i = 0; i < 16; i += 4) {
      e0 += __expf(acc[i]);
      e1 += __expf(acc[i + 1]);
      e2 += __expf(acc[i + 2]);
      e3 += __expf(acc[i + 3]);
    }
  }
  float lsum = (e0 + e1) + (e2 + e3);
  lsum += __shfl_xor(lsum, 32);            // combine the two hi-halves
  if (hi == 0) l4[wt * 32 + lo] = lsum;
  __syncthreads();
  if (tid < 32)
    linv[tid] = 1.0f / (l4[tid] + l4[32 + tid] + l4[64 + tid] + l4[96 + tid]);
  __syncthreads();

  // per-register normalizers for the NORMAL-orientation sweep 2
  float linv_r[16];
#pragma unroll
  for (int i = 0; i < 16; ++i)
    linv_r[i] = linv[(i & 3) + 8 * (i >> 2) + 4 * hi];

  // ---------------- sweep 2: write attn, accumulate O ----------------
  f32x16 oacc0 = {}, oacc1 = {};
  bf16* pw = plds + wt * 1280;                     // wave-private P tile
  float* aout = attn_out + (size_t)b * SB + (size_t)m0 * S;

  bf16x8 kA[4], vA[4], kB[4], vB[4];
  {
    // preload c = 0
    const int t1 = wt * 32;
    const bf16* krow = kbase + (size_t)(t1 + lo) * 64 + hi * 8;
    kA[0] = *(const bf16x8*)(krow);
    kA[1] = *(const bf16x8*)(krow + 16);
    kA[2] = *(const bf16x8*)(krow + 32);
    kA[3] = *(const bf16x8*)(krow + 48);
    const bf16* vrow = vbase + (size_t)lo * S + t1 + 8 * hi;
    vA[0] = *(const bf16x8*)(vrow);
    vA[1] = *(const bf16x8*)(vrow + 16);
    vA[2] = *(const bf16x8*)(vrow + (size_t)32 * S);
    vA[3] = *(const bf16x8*)(vrow + (size_t)32 * S + 16);
  }

  auto body = [&](int c_cur, int c_nxt,
                  bf16x8 (&kc)[4], bf16x8 (&vc)[4],
                  bf16x8 (&kn)[4], bf16x8 (&vn)[4]) {
    const int t0 = c_cur * 128 + wt * 32;
    const int t1 = c_nxt * 128 + wt * 32;
    // --- issue NEXT iteration's loads first (before this iter's stores) ---
    const bf16* krow = kbase + (size_t)(t1 + lo) * 64 + hi * 8;
    kn[0] = *(const bf16x8*)(krow);
    kn[1] = *(const bf16x8*)(krow + 16);
    kn[2] = *(const bf16x8*)(krow + 32);
    kn[3] = *(const bf16x8*)(krow + 48);
    const bf16* vrow = vbase + (size_t)lo * S + t1 + 8 * hi;
    vn[0] = *(const bf16x8*)(vrow);
    vn[1] = *(const bf16x8*)(vrow + 16);
    vn[2] = *(const bf16x8*)(vrow + (size_t)32 * S);
    vn[3] = *(const bf16x8*)(vrow + (size_t)32 * S + 16);

    // --- S = Q K^T on the CURRENT (already in-flight) fragments ---
    f32x16 acc = {};
    acc = MFMA(qf[0], kc[0], acc);
    acc = MFMA(qf[1], kc[1], acc);
    acc = MFMA(qf[2], kc[2], acc);
    acc = MFMA(qf[3], kc[3], acc);

#pragma unroll
    for (int i = 0; i < 16; ++i) acc[i] = __expf(acc[i]) * linv_r[i];

    // P -> LDS (bf16), 2-way bank pattern (free)
#pragma unroll
    for (int i = 0; i < 16; ++i) {
      int row = (i & 3) + 8 * (i >> 2) + 4 * hi;
      pw[row * 40 + lo] = (bf16)acc[i];
    }
    // PV: O[32 x 64] += P(32x32) @ V(32x64)
    bf16x8 pf0 = *(const bf16x8*)(pw + lo * 40 + 8 * hi);
    bf16x8 pf1 = *(const bf16x8*)(pw + lo * 40 + 16 + 8 * hi);
    oacc0 = MFMA(pf0, vc[0], oacc0);
    oacc0 = MFMA(pf1, vc[1], oacc0);
    oacc1 = MFMA(pf0, vc[2], oacc1);
    oacc1 = MFMA(pf1, vc[3], oacc1);

    // --- NT attn stores LAST (coalesced: 2 rows x 128B per instruction) ---
    float* ab = aout + t0 + lo;
#pragma unroll
    for (int i = 0; i < 16; ++i) {
      int row = (i & 3) + 8 * (i >> 2) + 4 * hi;
      __builtin_nontemporal_store(acc[i], ab + (size_t)row * S);
    }
  };

#pragma unroll 1
  for (int c = 0; c < 64; c += 2) {
    body(c, c + 1, kA, vA, kB, vB);
    body(c + 1, (c + 2) & 63, kB, vB, kA, vA);  // wrap prefetch is harmless
  }

  // reduce partial O across the 4 waves
#pragma unroll
  for (int i = 0; i < 16; ++i) {
    int row = (i & 3) + 8 * (i >> 2) + 4 * hi;
    atomicAdd(&olds[row * 65 + lo], oacc0[i]);
    atomicAdd(&olds[row * 65 + 32 + lo], oacc1[i]);
  }
  __syncthreads();
#pragma unroll
  for (int k = 0; k < 8; ++k) {
    int idx = k * 256 + tid;
    int row = idx >> 6, col = idx & 63;
    o_ws[((size_t)b * S + m0 + row) * 64 + col] = olds[row * 65 + col];
  }
}

// ---------------------------------------------------------------------------
// K3/K4: MLP with compensated bf16 MFMA (hi/lo split, 3-term products) so the
// MLP contributes ~2^-17 relative error. gelu exact via erff.
// ---------------------------------------------------------------------------
__device__ inline float gelu_exact(float v) {
  return 0.5f * v * (1.0f + erff(v * 0.70710678118654752f));
}

__global__ __launch_bounds__(256) void mlp1_kernel(
    const float* __restrict__ o_ws, const float* __restrict__ w1,
    const float* __restrict__ b1, bf16* __restrict__ hhi, bf16* __restrict__ hlo)
{
  const int tid = threadIdx.x;
  const int lane = tid & 63;
  const int wid = tid >> 6;
  const int lo = lane & 31, hi = lane >> 5;
  const int mt = blockIdx.x & 31, nt = blockIdx.x >> 5;
  const int m0 = mt * 64 + (wid & 1) * 32;
  const int f0 = nt * 64 + (wid >> 1) * 32;

  f32x16 acc = {};
  const float* arow = o_ws + (size_t)(m0 + lo) * 512 + hi * 8;
  const float* brow = w1 + (size_t)(f0 + lo) * 512 + hi * 8;
#pragma unroll 1
  for (int s = 0; s < 32; ++s) {
    const float* pa = arow + 16 * s;
    const float* pb = brow + 16 * s;
    bf16x8 ah, al, bh, bl;
#pragma unroll
    for (int j = 0; j < 8; ++j) {
      float a = pa[j];  bf16 h = (bf16)a;  ah[j] = h;  al[j] = (bf16)(a - (float)h);
      float bv = pb[j]; bf16 g = (bf16)bv; bh[j] = g;  bl[j] = (bf16)(bv - (float)g);
    }
    acc = MFMA(ah, bh, acc);
    acc = MFMA(ah, bl, acc);
    acc = MFMA(al, bh, acc);
  }
  const int f = f0 + lo;
  const float bias = b1[f];
#pragma unroll
  for (int i = 0; i < 16; ++i) {
    int m = m0 + (i & 3) + 8 * (i >> 2) + 4 * hi;
    float gv = gelu_exact(acc[i] + bias);
    bf16 h = (bf16)gv;
    hhi[(size_t)m * 1024 + f] = h;
    hlo[(size_t)m * 1024 + f] = (bf16)(gv - (float)h);
  }
}

__global__ __launch_bounds__(256) void mlp2_kernel(
    const bf16* __restrict__ hhi, const bf16* __restrict__ hlo,
    const float* __restrict__ w2, const float* __restrict__ b2,
    float* __restrict__ out2)
{
  const int tid = threadIdx.x;
  const int lane = tid & 63;
  const int wid = tid >> 6;
  const int lo = lane & 31, hi = lane >> 5;
  const int mt = blockIdx.x & 31, nt = blockIdx.x >> 5;
  const int m0 = mt * 64 + (wid & 1) * 32;
  const int e0 = nt * 64 + (wid >> 1) * 32;

  f32x16 acc = {};
  const bf16* ahr = hhi + (size_t)(m0 + lo) * 1024 + hi * 8;
  const bf16* alr = hlo + (size_t)(m0 + lo) * 1024 + hi * 8;
  const float* brow = w2 + (size_t)(e0 + lo) * 1024 + hi * 8;
#pragma unroll 1
  for (int s = 0; s < 64; ++s) {
    bf16x8 ah = *(const bf16x8*)(ahr + 16 * s);
    bf16x8 al = *(const bf16x8*)(alr + 16 * s);
    const float* pb = brow + 16 * s;
    bf16x8 bh, bl;
#pragma unroll
    for (int j = 0; j < 8; ++j) {
      float bv = pb[j]; bf16 g = (bf16)bv; bh[j] = g; bl[j] = (bf16)(bv - (float)g);
    }
    acc = MFMA(ah, bh, acc);
    acc = MFMA(al, bh, acc);
    acc = MFMA(ah, bl, acc);
  }
  const int e = e0 + lo;
  const float bias = b2[e];
#pragma unroll
  for (int i = 0; i < 16; ++i) {
    int m = m0 + (i & 3) + 8 * (i >> 2) + 4 * hi;
    out2[(size_t)m * 512 + e] = acc[i] + bias;
  }
}

// ---------------------------------------------------------------------------
extern "C" void kernel_launch(void* const* d_in, const int* in_sizes, int n_in,
                              void* d_out, int out_size, void* d_ws, size_t ws_size,
                              hipStream_t stream) {
  const float* x  = (const float*)d_in[0];
  const float* wq = (const float*)d_in[1];
  const float* wk = (const float*)d_in[2];
  const float* wv = (const float*)d_in[3];
  const float* w1 = (const float*)d_in[4];
  const float* b1 = (const float*)d_in[5];
  const float* w2 = (const float*)d_in[6];
  const float* b2 = (const float*)d_in[7];
  float* out = (float*)d_out;

  char* ws = (char*)d_ws;
  bf16* qb   = (bf16*)(ws);                       // 2 MB
  bf16* kb   = (bf16*)(ws + (2u << 20));          // 2 MB
  bf16* vtb  = (bf16*)(ws + (4u << 20));          // 2 MB (transposed V)
  float* ob  = (float*)(ws + (6u << 20));         // 4 MB (attention output)
  bf16* hhi  = (bf16*)(ws + (10u << 20));         // 4 MB
  bf16* hlo  = (bf16*)(ws + (14u << 20));         // 4 MB  -> 18 MB total

  qkv_kernel<<<512, 64, 0, stream>>>(x, wq, wk, wv, qb, kb, vtb);
  attn_kernel<<<512, 256, 0, stream>>>(qb, kb, vtb, out, ob);
  mlp1_kernel<<<512, 256, 0, stream>>>(ob, w1, b1, hhi, hlo);
  mlp2_kernel<<<256, 256, 0, stream>>>(hhi, hlo, w2, b2, out + ATTN_ELEMS);
}